// Round 11
// baseline (146.869 us; speedup 1.0000x reference)
//
#include <hip/hip_runtime.h>
#include <math.h>

#define B   8
#define NA  33600
#define M   64
#define NC  80
#define KK  13
#define EPSF 1e-9f
#define PIF 3.14159265358979323846f

#define CHK   256               // anchors per build block
#define NCHK  132               // ceil(NA/CHK)
#define BCAP  96                // positives cap per build block (expected ~8)
#define REG   (1 + 2 * BCAP)    // region words: count | packed | met-bits
#define FCAP  4096              // flat positives cap per batch (expected ~1000)
#define GCAP  96                // per-gt positives cap (R9 passed with 96)

// ---------------------------------------------------------------- helpers

__device__ __forceinline__ float circle_iou(float gx, float gy, float gr,
                                            float px, float py, float pr) {
    float dx = gx - px, dy = gy - py;
    float d  = sqrtf(dx * dx + dy * dy + 1e-12f);
    float r0sq = gr * gr, r1sq = pr * pr;
    float d1 = (r0sq - r1sq + d * d) / (2.0f * d);
    float d2 = d - d1;
    float t0 = fminf(fmaxf(d1 / fmaxf(gr, EPSF), -1.0f), 1.0f);
    float t1 = fminf(fmaxf(d2 / fmaxf(pr, EPSF), -1.0f), 1.0f);
    float a0 = r0sq * acosf(t0) - d1 * sqrtf(fmaxf(r0sq - d1 * d1, 0.0f));
    float a1 = r1sq * acosf(t1) - d2 * sqrtf(fmaxf(r1sq - d2 * d2, 0.0f));
    float lens = a0 + a1;
    float rmin = fminf(gr, pr);
    float contained = PIF * rmin * rmin;
    float inter = (d >= gr + pr) ? 0.0f
                : ((d <= fabsf(gr - pr)) ? contained : lens);
    float uni = PIF * r0sq + PIF * r1sq - inter;
    return (uni > 0.0f) ? inter / uni : 0.0f;
}

// ---------------------------------------------------------------- K1: per-anchor dense build
// Reads pd_circles ONCE, coalesced. Positives -> per-block regions
// [count | packed(a<<6|m) | met-bits]; counts written unconditionally
// (no pre-zeroing). Also writes assigned/am_val defaults.

__global__ __launch_bounds__(CHK)
void k_build(const float* __restrict__ pd_scores, const float* __restrict__ pd_circles,
             const float* __restrict__ anc, const int* __restrict__ gt_labels,
             const float* __restrict__ gt_circles, const float* __restrict__ mask_gt,
             int* __restrict__ breg, int* __restrict__ assigned,
             float* __restrict__ am_val) {
    int chunk = blockIdx.x;
    int b     = blockIdx.y;
    int tid   = threadIdx.x;

    __shared__ float s_gx[M], s_gy[M], s_gr[M];
    __shared__ int   s_gl[M], s_act[M];
    __shared__ int   s_cnt;
    __shared__ int   s_pk[BCAP];
    __shared__ int   s_mv[BCAP];

    if (tid < M) {
        int gi = b * M + tid;
        s_act[tid] = mask_gt[gi] > 0.0f;
        s_gx[tid] = gt_circles[gi * 3 + 0];
        s_gy[tid] = gt_circles[gi * 3 + 1];
        s_gr[tid] = gt_circles[gi * 3 + 2];
        int l = gt_labels[gi];
        s_gl[tid] = l < 0 ? 0 : (l > NC - 1 ? NC - 1 : l);
    }
    if (tid == 0) s_cnt = 0;
    __syncthreads();

    int a = chunk * CHK + tid;
    if (a < NA) {
        int i = b * NA + a;
        assigned[i] = -1;                  // defaults; winners fixed up in K2
        am_val[i]   = 0.0f;
        float2 ap = reinterpret_cast<const float2*>(anc)[a];
        float px = pd_circles[(size_t)i * 3 + 0];   // dense coalesced stream
        float py = pd_circles[(size_t)i * 3 + 1];
        float pr = pd_circles[(size_t)i * 3 + 2];

        for (int m = 0; m < M; m++) {
            if (!s_act[m]) continue;                          // wave-uniform
            float gx = s_gx[m], gy = s_gy[m], gr = s_gr[m];
            float dxa = ap.x - gx, dya = ap.y - gy;
            if (!(sqrtf(dxa * dxa + dya * dya) < gr)) continue;   // in-circle?
            float cdx = gx - px, cdy = gy - py;
            float dc = sqrtf(cdx * cdx + cdy * cdy + 1e-12f);
            if (dc >= gr + pr) continue;                      // disjoint -> iou 0
            float ov = circle_iou(gx, gy, gr, px, py, pr);    // gmask == 1 here
            if (!(ov > 0.0f)) continue;
            float sc = pd_scores[(size_t)i * NC + s_gl[m]];   // rare gather
            float o2 = ov * ov;
            float met = sc * (o2 * o2 * o2);                  // score^1 * ov^6
            if (met > 0.0f) {
                int p = atomicAdd(&s_cnt, 1);
                if (p < BCAP) { s_pk[p] = (a << 6) | m; s_mv[p] = __float_as_int(met); }
            }
        }
    }
    __syncthreads();

    int cnt = s_cnt; if (cnt > BCAP) cnt = BCAP;
    int rbase = (b * NCHK + chunk) * REG;
    if (tid == 0) breg[rbase] = cnt;
    if (tid < cnt) {
        breg[rbase + 1 + tid]        = s_pk[tid];
        breg[rbase + 1 + BCAP + tid] = s_mv[tid];
    }
}

// ---------------------------------------------------------------- K2: per-batch select + resolve + posmax
// Gathers positives to flat LDS; per-wave per-gt top-13 (ported); reuses the
// flat pool as u8 anchor-histogram for conflict resolution (ported from R10).

__global__ __launch_bounds__(1024)
void k_sel_resolve(const float* __restrict__ pd_scores, const float* __restrict__ pd_circles,
                   const float* __restrict__ anc, const int* __restrict__ gt_labels,
                   const float* __restrict__ gt_circles, const float* __restrict__ mask_gt,
                   const int* __restrict__ breg,
                   int* __restrict__ assigned, float* __restrict__ am_val,
                   int* __restrict__ pos_align_i, int* __restrict__ pos_ov_i) {
    int b    = blockIdx.x;
    int tid  = threadIdx.x;
    int lane = tid & 63;
    int w    = tid >> 6;                    // 16 waves

    __shared__ unsigned s_pool[8448];       // flat pk[0..4095], mv[4096..8191]; later u8 histogram [0..8400]
    __shared__ int   s_gla[16][GCAP];
    __shared__ float s_glv[16][GCAP];
    __shared__ int   s_glcnt[16];
    __shared__ int   s_win[M * KK];
    __shared__ float s_wmet[M * KK];
    __shared__ float s_gx[M], s_gy[M], s_gr[M];
    __shared__ int   s_gl[M], s_act[M];
    __shared__ int   s_posa[M], s_poso[M];
    __shared__ int   s_multi[M * KK];
    __shared__ int   s_nm, s_fcnt;

    if (tid < M) {
        int gi = b * M + tid;
        s_act[tid] = mask_gt[gi] > 0.0f;
        s_gx[tid] = gt_circles[gi * 3 + 0];
        s_gy[tid] = gt_circles[gi * 3 + 1];
        s_gr[tid] = gt_circles[gi * 3 + 2];
        int l = gt_labels[gi];
        s_gl[tid] = l < 0 ? 0 : (l > NC - 1 ? NC - 1 : l);
        s_posa[tid] = 0; s_poso[tid] = 0;
    }
    if (tid == 0) { s_nm = 0; s_fcnt = 0; }
    __syncthreads();

    // ---- gather flat positives from the batch's 132 regions
    for (int r = w; r < NCHK; r += 16) {
        int rbase = (b * NCHK + r) * REG;
        int cnt = breg[rbase];
        int ofs = 0;
        if (lane == 0) ofs = atomicAdd(&s_fcnt, cnt);
        ofs = __shfl(ofs, 0);
        for (int j = lane; j < cnt; j += 64) {
            int dst = ofs + j;
            if (dst < FCAP) {
                s_pool[dst]        = (unsigned)breg[rbase + 1 + j];
                s_pool[4096 + dst] = (unsigned)breg[rbase + 1 + BCAP + j];
            }
        }
    }
    __syncthreads();
    int fcnt = s_fcnt; if (fcnt > FCAP) fcnt = FCAP;

    // ---- selection: wave w handles gts 4w..4w+3
    for (int q = 0; q < 4; q++) {
        int m = w * 4 + q;
        bool active = s_act[m] != 0;
        if (lane == 0) s_glcnt[w] = 0;
        __syncthreads();
        if (active) {
            for (int i = lane; i < fcnt; i += 64) {
                unsigned pk = s_pool[i];
                if ((pk & 63u) == (unsigned)m) {
                    float v = __uint_as_float(s_pool[4096 + i]);
                    int p = atomicAdd(&s_glcnt[w], 1);
                    if (p < GCAP) { s_gla[w][p] = (int)(pk >> 6); s_glv[w][p] = v; }
                }
            }
        }
        __syncthreads();
        int cnt = 0;
        if (active) { cnt = s_glcnt[w]; if (cnt > GCAP) cnt = GCAP; }

        // 13 rounds of argmax (val desc, anchor asc) == lax.top_k order
        for (int k = 0; k < KK; k++) {
            if (!active) break;
            float bv = 0.0f; int ba = 0x7fffffff; int bp = -1;
            for (int i = lane; i < cnt; i += 64) {
                float v = s_glv[w][i];
                if (v > 0.0f) {
                    int a = s_gla[w][i];
                    if (v > bv || (v == bv && a < ba)) { bv = v; ba = a; bp = i; }
                }
            }
            for (int off = 32; off > 0; off >>= 1) {
                float v2 = __shfl_xor(bv, off);
                int   a2 = __shfl_xor(ba, off);
                int   p2 = __shfl_xor(bp, off);
                if (v2 > bv || (v2 == bv && a2 < ba)) { bv = v2; ba = a2; bp = p2; }
            }
            if (lane == 0) {
                int slot = m * KK + k;
                if (bp >= 0) { s_win[slot] = ba; s_wmet[slot] = bv; s_glv[w][bp] = -1.0f; }
                else         { s_win[slot] = -2; s_wmet[slot] = 0.0f; }
            }
        }

        if (active) {
            // zero-fill WITHOUT gathers: met==0 <=> anchor absent from the
            // gt's positive list -> lowest absent indices (top_k zero tie-break)
            int defmask = 0;
            for (int k = 0; k < KK; k++) if (s_win[m * KK + k] == -2) defmask |= (1 << k);
            if (defmask) {
                int base = 0;
                while (defmask && base < NA) {
                    int idx = base + lane;
                    bool freez = (idx < NA);
                    for (int i = 0; i < cnt; i++)
                        freez = freez && (s_gla[w][i] != idx);
                    unsigned long long msk = __ballot(freez);
                    while (msk && defmask) {
                        int bit = __ffsll((long long)msk) - 1; msk &= msk - 1;
                        int k2  = __ffs(defmask) - 1;          defmask &= defmask - 1;
                        if (lane == 0) { s_win[m * KK + k2] = base + bit; s_wmet[m * KK + k2] = 0.0f; }
                    }
                    base += 64;
                }
                while (defmask) {
                    int k2 = __ffs(defmask) - 1; defmask &= defmask - 1;
                    if (lane == 0) s_win[m * KK + k2] = -1;
                }
            }
            // winners enter mask_pos only if anchor center inside the gt circle
            if (lane < KK) {
                int slot = m * KK + lane;
                int a = s_win[slot];
                if (a >= 0) {
                    float ax = anc[2 * a], ay = anc[2 * a + 1];
                    float dx = ax - s_gx[m], dy = ay - s_gy[m];
                    if (!(sqrtf(dx * dx + dy * dy) < s_gr[m])) s_win[slot] = -1;
                } else s_win[slot] = -1;
            }
        } else {
            if (lane < KK) s_win[m * KK + lane] = -1;
        }
    }
    __syncthreads();

    // ---- histogram (reuse pool as u8-packed counts over NA)
    for (int i = tid; i < NA / 4 + 1; i += 1024) s_pool[i] = 0;
    __syncthreads();
    int mya = -1, mym = -1; unsigned prev = 0;
    if (tid < M * KK) {
        int a = s_win[tid];
        mym = tid / KK;
        if (a >= 0) {
            mya = a;
            unsigned sh = 8u * (a & 3);
            unsigned old = atomicAdd(&s_pool[a >> 2], 1u << sh);
            prev = (old >> sh) & 0xFFu;
        }
    }
    __syncthreads();

    // singles resolve; first-toucher of multis enqueues
    if (mya >= 0) {
        unsigned c = (s_pool[mya >> 2] >> (8u * (mya & 3))) & 0xFFu;
        if (c == 1u) {
            int i = b * NA + mya;
            float met = s_wmet[tid];
            float gx = s_gx[mym], gy = s_gy[mym], gr = s_gr[mym];
            float px = pd_circles[(size_t)i * 3 + 0];
            float py = pd_circles[(size_t)i * 3 + 1];
            float pr = pd_circles[(size_t)i * 3 + 2];
            float cdx = gx - px, cdy = gy - py;
            float dc = sqrtf(cdx * cdx + cdy * cdy + 1e-12f);
            float ov = (dc >= gr + pr) ? 0.0f : circle_iou(gx, gy, gr, px, py, pr);
            assigned[i] = mym;
            am_val[i]   = met;
            atomicMax(&s_posa[mym], __float_as_int(met));   // values >= 0
            atomicMax(&s_poso[mym], __float_as_int(ov));
        } else if (prev == 0u) {
            int p = atomicAdd(&s_nm, 1); s_multi[p] = mya;
        }
    }
    __syncthreads();

    // multis: one anchor per wave; lane = gt; argmax over masked overlaps
    int nm = s_nm;
    for (int r = w; r < nm; r += 16) {
        int am_ = s_multi[r];
        int i = b * NA + am_;
        float ax = anc[2 * am_], ay = anc[2 * am_ + 1];
        float px = pd_circles[(size_t)i * 3 + 0];
        float py = pd_circles[(size_t)i * 3 + 1];
        float pr = pd_circles[(size_t)i * 3 + 2];
        float ov = 0.0f;
        if (s_act[lane]) {
            float gx = s_gx[lane], gy = s_gy[lane], gr = s_gr[lane];
            float dx = ax - gx, dy = ay - gy;
            if (sqrtf(dx * dx + dy * dy) < gr) {
                float cdx = gx - px, cdy = gy - py;
                float dc = sqrtf(cdx * cdx + cdy * cdy + 1e-12f);
                ov = (dc >= gr + pr) ? 0.0f : circle_iou(gx, gy, gr, px, py, pr);
            }
        }
        float bv = ov; int bmx = lane;
        for (int off = 32; off > 0; off >>= 1) {
            float v2 = __shfl_xor(bv, off);
            int   m2 = __shfl_xor(bmx, off);
            if (v2 > bv || (v2 == bv && m2 < bmx)) { bv = v2; bmx = m2; }
        }
        if (lane == 0) {
            float met = 0.0f;
            if (bv > 0.0f) {
                float sc = pd_scores[(size_t)i * NC + s_gl[bmx]];
                float o2 = bv * bv;
                met = sc * (o2 * o2 * o2);
            }
            assigned[i] = bmx;
            am_val[i]   = met;
            atomicMax(&s_posa[bmx], __float_as_int(met));
            atomicMax(&s_poso[bmx], __float_as_int(bv));
        }
    }
    __syncthreads();

    if (tid < M) {
        pos_align_i[b * M + tid] = s_posa[tid];
        pos_ov_i[b * M + tid]    = s_poso[tid];
    }
}

// ---------------------------------------------------------------- K3: fused outputs (93 MB write)

__global__ void k_out(const int* __restrict__ assigned, const float* __restrict__ am_val,
                      const int* __restrict__ pos_align_i, const int* __restrict__ pos_ov_i,
                      const int* __restrict__ gt_labels, const float* __restrict__ gt_circles,
                      float* __restrict__ out_labels, float* __restrict__ out_circ,
                      float* __restrict__ out_scores, float* __restrict__ out_fg,
                      float* __restrict__ out_gtidx) {
    const int QPR = NC / 4;                      // 20 float4s per score row
    int q = blockIdx.x * blockDim.x + threadIdx.x;
    if (q >= B * NA * QPR) return;
    int row = q / QPR;
    int c0  = (q - row * QPR) * 4;
    int b   = row / NA;

    int g = assigned[row];
    int gidx = 0; float fg = 0.0f; float norm = 0.0f;
    if (g >= 0) {
        gidx = g; fg = 1.0f;
        float pa = __int_as_float(pos_align_i[b * M + g]);
        float po = __int_as_float(pos_ov_i[b * M + g]);
        norm = am_val[row] * po / (pa + EPSF);
    }
    int rawl = gt_labels[b * M + gidx];
    int lbl = rawl < 0 ? 0 : rawl;               // clip(.., 0, None)

    float4 v = make_float4(0.f, 0.f, 0.f, 0.f);
    if (g >= 0) {
        int off = lbl - c0;
        if (off >= 0 && off < 4) ((float*)&v)[off] = norm;
    }
    reinterpret_cast<float4*>(out_scores)[q] = v;

    if (c0 == 0) {
        out_labels[row] = (float)lbl;
        out_circ[(size_t)row * 3 + 0] = gt_circles[(b * M + gidx) * 3 + 0];
        out_circ[(size_t)row * 3 + 1] = gt_circles[(b * M + gidx) * 3 + 1];
        out_circ[(size_t)row * 3 + 2] = gt_circles[(b * M + gidx) * 3 + 2];
        out_fg[row]    = fg;
        out_gtidx[row] = (float)gidx;
    }
}

// ---------------------------------------------------------------- launch

extern "C" void kernel_launch(void* const* d_in, const int* in_sizes, int n_in,
                              void* d_out, int out_size, void* d_ws, size_t ws_size,
                              hipStream_t stream) {
    const float* pd_scores  = (const float*)d_in[0];   // (B, NA, NC)
    const float* pd_circles = (const float*)d_in[1];   // (B, NA, 3)
    const float* anc        = (const float*)d_in[2];   // (NA, 2)
    const int*   gt_labels  = (const int*)  d_in[3];   // (B, M, 1)
    const float* gt_circles = (const float*)d_in[4];   // (B, M, 3)
    const float* mask_gt    = (const float*)d_in[5];   // (B, M, 1)

    // workspace layout
    char* w = (char*)d_ws;
    int*   breg        = (int*)w;   w += (size_t)B * NCHK * REG * sizeof(int);
    int*   assigned    = (int*)w;   w += (size_t)B * NA * sizeof(int);
    float* am_val      = (float*)w; w += (size_t)B * NA * sizeof(float);
    int*   pos_align_i = (int*)w;   w += (size_t)B * M * sizeof(int);
    int*   pos_ov_i    = (int*)w;   w += (size_t)B * M * sizeof(int);

    // output layout (concat in return order, float32)
    float* out        = (float*)d_out;
    float* out_labels = out;                              // B*NA
    float* out_circ   = out_labels + (size_t)B * NA;      // B*NA*3
    float* out_scores = out_circ + (size_t)B * NA * 3;    // B*NA*NC
    float* out_fg     = out_scores + (size_t)B * NA * NC; // B*NA
    float* out_gtidx  = out_fg + (size_t)B * NA;          // B*NA

    dim3 gb(NCHK, B);
    k_build<<<gb, CHK, 0, stream>>>(pd_scores, pd_circles, anc, gt_labels,
                                    gt_circles, mask_gt, breg, assigned, am_val);

    k_sel_resolve<<<B, 1024, 0, stream>>>(pd_scores, pd_circles, anc, gt_labels,
                                          gt_circles, mask_gt, breg,
                                          assigned, am_val, pos_align_i, pos_ov_i);

    int nq = B * NA * (NC / 4);
    k_out<<<(nq + 255) / 256, 256, 0, stream>>>(assigned, am_val,
                                                pos_align_i, pos_ov_i,
                                                gt_labels, gt_circles,
                                                out_labels, out_circ, out_scores,
                                                out_fg, out_gtidx);
}

// Round 12
// 113.067 us; speedup vs baseline: 1.2990x; 1.2990x over previous
//
#include <hip/hip_runtime.h>
#include <math.h>

#define B   8
#define NA  33600
#define M   64
#define NC  80
#define KK  13
#define EPSF 1e-9f
#define PIF 3.14159265358979323846f

#define NPOS 1536          // per-gt positive capacity (max in-circle ~1100)
#define SPB  (M * KK)      // 832 winner slots per batch
#define NDIS 256           // discover blocks: B * 32 gt-pairs

// ---------------------------------------------------------------- helpers

__device__ __forceinline__ float circle_iou(float gx, float gy, float gr,
                                            float px, float py, float pr) {
    float dx = gx - px, dy = gy - py;
    float d  = sqrtf(dx * dx + dy * dy + 1e-12f);
    float r0sq = gr * gr, r1sq = pr * pr;
    float d1 = (r0sq - r1sq + d * d) / (2.0f * d);
    float d2 = d - d1;
    float t0 = fminf(fmaxf(d1 / fmaxf(gr, EPSF), -1.0f), 1.0f);
    float t1 = fminf(fmaxf(d2 / fmaxf(pr, EPSF), -1.0f), 1.0f);
    float a0 = r0sq * acosf(t0) - d1 * sqrtf(fmaxf(r0sq - d1 * d1, 0.0f));
    float a1 = r1sq * acosf(t1) - d2 * sqrtf(fmaxf(r1sq - d2 * d2, 0.0f));
    float lens = a0 + a1;
    float rmin = fminf(gr, pr);
    float contained = PIF * rmin * rmin;
    float inter = (d >= gr + pr) ? 0.0f
                : ((d <= fabsf(gr - pr)) ? contained : lens);
    float uni = PIF * r0sq + PIF * r1sq - inter;
    return (uni > 0.0f) ? inter / uni : 0.0f;
}

// ---------------------------------------------------------------- K1: 2-gt dense-stream discovery + top-13
// One stream pass tests both gts of the pair; selection on waves 0/1.
// Winners carry (anchor, met, ov). Also inits assigned/am_val/pos arrays.

__global__ __launch_bounds__(1024)
void k_discover(const float* __restrict__ pd_scores, const float* __restrict__ pd_circles,
                const float* __restrict__ anc, const int* __restrict__ gt_labels,
                const float* __restrict__ gt_circles, const float* __restrict__ mask_gt,
                int* __restrict__ wlist, float* __restrict__ wmet, float* __restrict__ wov,
                int* __restrict__ assigned, float* __restrict__ am_val,
                int* __restrict__ pos_align_i, int* __restrict__ pos_ov_i) {
    int bid = blockIdx.x;
    int b   = bid >> 5;
    int j   = bid & 31;
    int m0  = 2 * j;
    int tid = threadIdx.x;

    // init disjoint slice of assigned/am_val (1050 per block) + pos arrays
    const int SL = (B * NA) / NDIS;            // 1050
    for (int i = tid; i < SL; i += 1024) {
        assigned[bid * SL + i] = -1;
        am_val[bid * SL + i]   = 0.0f;
    }
    if (j == 0 && tid < M) { pos_align_i[b * M + tid] = 0; pos_ov_i[b * M + tid] = 0; }

    __shared__ int   s_cnt[2];
    __shared__ int   s_pa[2][NPOS];
    __shared__ float s_pv[2][NPOS];
    __shared__ float s_po[2][NPOS];
    __shared__ int   s_win[2][KK];
    __shared__ float s_selv[2][KK], s_selo[2][KK];

    int bm0 = b * M + m0;
    bool act0 = mask_gt[bm0]     > 0.0f;
    bool act1 = mask_gt[bm0 + 1] > 0.0f;
    if (!act0 && !act1) {
        if (tid < KK) { wlist[bm0 * KK + tid] = -1; wlist[(bm0 + 1) * KK + tid] = -1; }
        return;
    }
    float gx0 = gt_circles[bm0 * 3 + 0], gy0 = gt_circles[bm0 * 3 + 1], gr0 = gt_circles[bm0 * 3 + 2];
    float gx1 = gt_circles[(bm0 + 1) * 3 + 0], gy1 = gt_circles[(bm0 + 1) * 3 + 1], gr1 = gt_circles[(bm0 + 1) * 3 + 2];
    int gl0 = gt_labels[bm0];     gl0 = gl0 < 0 ? 0 : (gl0 > NC - 1 ? NC - 1 : gl0);
    int gl1 = gt_labels[bm0 + 1]; gl1 = gl1 < 0 ? 0 : (gl1 > NC - 1 ? NC - 1 : gl1);

    if (tid < 2) s_cnt[tid] = 0;
    __syncthreads();

#define TRY(A_, AX_, AY_, PX_, PY_, PR_, G_, GX_, GY_, GR_, GL_) do {          \
        float dx_ = (AX_) - (GX_), dy_ = (AY_) - (GY_);                        \
        if (sqrtf(dx_ * dx_ + dy_ * dy_) < (GR_)) {                            \
            float cdx_ = (GX_) - (PX_), cdy_ = (GY_) - (PY_);                  \
            float dc_ = sqrtf(cdx_ * cdx_ + cdy_ * cdy_ + 1e-12f);             \
            if (dc_ < (GR_) + (PR_)) {                                         \
                float ov_ = circle_iou((GX_), (GY_), (GR_), (PX_), (PY_), (PR_)); \
                if (ov_ > 0.0f) {                                              \
                    float sc_ = pd_scores[((size_t)b * NA + (A_)) * NC + (GL_)]; \
                    float o2_ = ov_ * ov_;                                     \
                    float met_ = sc_ * (o2_ * o2_ * o2_);                      \
                    if (met_ > 0.0f) {                                         \
                        int p_ = atomicAdd(&s_cnt[G_], 1);                     \
                        if (p_ < NPOS) { s_pa[G_][p_] = (A_); s_pv[G_][p_] = met_; s_po[G_][p_] = ov_; } \
                    } } } } } while (0)

    // dense stream: 2 anchors / iter; anc float4 + pd 3x float2 (all coalesced)
    const float2* pdc2 = reinterpret_cast<const float2*>(pd_circles + (size_t)b * NA * 3);
    for (int q = tid; q < NA / 2; q += 1024) {
        float4 ap = reinterpret_cast<const float4*>(anc)[q];
        float2 p0 = pdc2[3 * q + 0];   // x0 y0
        float2 p1 = pdc2[3 * q + 1];   // r0 x1
        float2 p2 = pdc2[3 * q + 2];   // y1 r1
        int a0 = 2 * q, a1 = 2 * q + 1;
        if (act0) TRY(a0, ap.x, ap.y, p0.x, p0.y, p1.x, 0, gx0, gy0, gr0, gl0);
        if (act1) TRY(a0, ap.x, ap.y, p0.x, p0.y, p1.x, 1, gx1, gy1, gr1, gl1);
        if (act0) TRY(a1, ap.z, ap.w, p1.y, p2.x, p2.y, 0, gx0, gy0, gr0, gl0);
        if (act1) TRY(a1, ap.z, ap.w, p1.y, p2.x, p2.y, 1, gx1, gy1, gr1, gl1);
    }
#undef TRY
    __syncthreads();

    // selection: wave 0 -> gt m0, wave 1 -> gt m0+1; no barriers below
    int w = tid >> 6;
    if (w >= 2) return;
    int lane = tid & 63;
    int m  = m0 + w;
    int bm = b * M + m;
    bool act = w ? act1 : act0;
    if (!act) { if (lane < KK) wlist[bm * KK + lane] = -1; return; }
    float gx = w ? gx1 : gx0, gy = w ? gy1 : gy0, gr = w ? gr1 : gr0;
    int pcnt = s_cnt[w]; if (pcnt > NPOS) pcnt = NPOS;

    // 13 rounds of argmax (val desc, anchor asc) == lax.top_k order
    for (int k = 0; k < KK; k++) {
        float bv = 0.0f; int ba = 0x7fffffff; int bp = -1;
        for (int i = lane; i < pcnt; i += 64) {
            float v = s_pv[w][i];
            if (v > 0.0f) {
                int a = s_pa[w][i];
                if (v > bv || (v == bv && a < ba)) { bv = v; ba = a; bp = i; }
            }
        }
        for (int off = 32; off > 0; off >>= 1) {
            float v2 = __shfl_xor(bv, off);
            int   a2 = __shfl_xor(ba, off);
            int   p2 = __shfl_xor(bp, off);
            if (v2 > bv || (v2 == bv && a2 < ba)) { bv = v2; ba = a2; bp = p2; }
        }
        if (lane == 0) {
            if (bp >= 0) {
                s_win[w][k] = ba; s_selv[w][k] = bv; s_selo[w][k] = s_po[w][bp];
                s_pv[w][bp] = -1.0f;
            } else { s_win[w][k] = -2; s_selv[w][k] = 0.0f; s_selo[w][k] = 0.0f; }
        }
    }

    // zero-fill WITHOUT gathers: met==0 <=> anchor absent from positive list
    // -> lowest absent indices (lax.top_k zero tie-break)
    int defmask = 0;
    for (int k = 0; k < KK; k++) if (s_win[w][k] == -2) defmask |= (1 << k);
    if (defmask) {
        int base = 0;
        while (defmask && base < NA) {
            int idx = base + lane;
            bool freez = (idx < NA);
            for (int i = 0; i < pcnt; i++)
                freez = freez && (s_pa[w][i] != idx);
            unsigned long long msk = __ballot(freez);
            while (msk && defmask) {
                int bit = __ffsll((long long)msk) - 1; msk &= msk - 1;
                int k2  = __ffs(defmask) - 1;          defmask &= defmask - 1;
                if (lane == 0) s_win[w][k2] = base + bit;   // selv/selo stay 0
            }
            base += 64;
        }
        while (defmask) {
            int k2 = __ffs(defmask) - 1; defmask &= defmask - 1;
            if (lane == 0) s_win[w][k2] = -1;
        }
    }

    // winners enter mask_pos only if anchor center inside the gt circle
    if (lane < KK) {
        int a = s_win[w][lane];
        int outv = -1; float om = 0.0f, oo = 0.0f;
        if (a >= 0) {
            float ax = anc[2 * a], ay = anc[2 * a + 1];
            float dx = ax - gx, dy = ay - gy;
            if (sqrtf(dx * dx + dy * dy) < gr) {
                outv = a; om = s_selv[w][lane]; oo = s_selo[w][lane];
            }
        }
        wlist[bm * KK + lane] = outv;
        wmet[bm * KK + lane]  = om;
        wov[bm * KK + lane]   = oo;
    }
}

// ---------------------------------------------------------------- K2: winner-slot resolve (32 blocks, dup-scan, no histogram)

__global__ __launch_bounds__(256)
void k_resolve(const float* __restrict__ pd_scores, const float* __restrict__ pd_circles,
               const float* __restrict__ anc, const int* __restrict__ gt_labels,
               const float* __restrict__ gt_circles, const float* __restrict__ mask_gt,
               const int* __restrict__ wlist, const float* __restrict__ wmet,
               const float* __restrict__ wov,
               int* __restrict__ assigned, float* __restrict__ am_val,
               int* __restrict__ pos_align_i, int* __restrict__ pos_ov_i) {
    int bid  = blockIdx.x;                // 32 = B x 4
    int b    = bid >> 2;
    int part = bid & 3;
    int tid  = threadIdx.x;

    __shared__ int   s_wl[SPB];
    __shared__ float s_wm[SPB], s_wo[SPB];
    __shared__ float s_gx[M], s_gy[M], s_gr[M];
    __shared__ int   s_gl[M], s_act[M];

    if (tid < M) {
        int gi = b * M + tid;
        s_act[tid] = mask_gt[gi] > 0.0f;
        s_gx[tid] = gt_circles[gi * 3 + 0];
        s_gy[tid] = gt_circles[gi * 3 + 1];
        s_gr[tid] = gt_circles[gi * 3 + 2];
        int l = gt_labels[gi];
        s_gl[tid] = l < 0 ? 0 : (l > NC - 1 ? NC - 1 : l);
    }
    for (int i = tid; i < SPB; i += 256) {
        s_wl[i] = wlist[b * SPB + i];
        s_wm[i] = wmet[b * SPB + i];
        s_wo[i] = wov[b * SPB + i];
    }
    __syncthreads();

    int slot = part * (SPB / 4) + tid;    // 208 slots per part
    if (tid >= SPB / 4) return;
    int a = s_wl[slot];
    if (a < 0) return;

    // dup-scan: count + lowest lister slot (deterministic owner)
    int cnt = 0, minslot = SPB;
    for (int i2 = 0; i2 < SPB; i2++)
        if (s_wl[i2] == a) { cnt++; if (i2 < minslot) minslot = i2; }
    if (minslot != slot) return;          // exactly one owner per anchor

    int i = b * NA + a;
    if (cnt == 1) {
        int m = slot / KK;
        assigned[i] = m;
        am_val[i]   = s_wm[slot];
        atomicMax(&pos_align_i[b * M + m], __float_as_int(s_wm[slot]));  // >= 0
        atomicMax(&pos_ov_i[b * M + m],    __float_as_int(s_wo[slot]));
    } else {
        // fg > 1: jnp.argmax over masked overlaps, lowest gt index wins ties
        float ax = anc[2 * a], ay = anc[2 * a + 1];
        float px = pd_circles[(size_t)i * 3 + 0];
        float py = pd_circles[(size_t)i * 3 + 1];
        float pr = pd_circles[(size_t)i * 3 + 2];
        float best = -1.0f; int g = 0;
        for (int mm = 0; mm < M; mm++) {
            float ovv = 0.0f;
            if (s_act[mm]) {
                float gx = s_gx[mm], gy = s_gy[mm], gr = s_gr[mm];
                float dx = ax - gx, dy = ay - gy;
                if (sqrtf(dx * dx + dy * dy) < gr) {
                    float cdx = gx - px, cdy = gy - py;
                    float dc = sqrtf(cdx * cdx + cdy * cdy + 1e-12f);
                    ovv = (dc >= gr + pr) ? 0.0f : circle_iou(gx, gy, gr, px, py, pr);
                }
            }
            if (ovv > best) { best = ovv; g = mm; }
        }
        float met = 0.0f;
        if (best > 0.0f) {
            float sc = pd_scores[(size_t)i * NC + s_gl[g]];
            float o2 = best * best;
            met = sc * (o2 * o2 * o2);
        }
        assigned[i] = g;
        am_val[i]   = met;
        atomicMax(&pos_align_i[b * M + g], __float_as_int(met));
        atomicMax(&pos_ov_i[b * M + g],    __float_as_int(fmaxf(best, 0.0f)));
    }
}

// ---------------------------------------------------------------- K3: fused outputs (93 MB write)

__global__ void k_out(const int* __restrict__ assigned, const float* __restrict__ am_val,
                      const int* __restrict__ pos_align_i, const int* __restrict__ pos_ov_i,
                      const int* __restrict__ gt_labels, const float* __restrict__ gt_circles,
                      float* __restrict__ out_labels, float* __restrict__ out_circ,
                      float* __restrict__ out_scores, float* __restrict__ out_fg,
                      float* __restrict__ out_gtidx) {
    const int QPR = NC / 4;                      // 20 float4s per score row
    int q = blockIdx.x * blockDim.x + threadIdx.x;
    if (q >= B * NA * QPR) return;
    int row = q / QPR;
    int c0  = (q - row * QPR) * 4;
    int b   = row / NA;

    int g = assigned[row];
    int gidx = 0; float fg = 0.0f; float norm = 0.0f;
    if (g >= 0) {
        gidx = g; fg = 1.0f;
        float pa = __int_as_float(pos_align_i[b * M + g]);
        float po = __int_as_float(pos_ov_i[b * M + g]);
        norm = am_val[row] * po / (pa + EPSF);
    }
    int rawl = gt_labels[b * M + gidx];
    int lbl = rawl < 0 ? 0 : rawl;               // clip(.., 0, None)

    float4 v = make_float4(0.f, 0.f, 0.f, 0.f);
    if (g >= 0) {
        int off = lbl - c0;
        if (off >= 0 && off < 4) ((float*)&v)[off] = norm;
    }
    reinterpret_cast<float4*>(out_scores)[q] = v;

    if (c0 == 0) {
        out_labels[row] = (float)lbl;
        out_circ[(size_t)row * 3 + 0] = gt_circles[(b * M + gidx) * 3 + 0];
        out_circ[(size_t)row * 3 + 1] = gt_circles[(b * M + gidx) * 3 + 1];
        out_circ[(size_t)row * 3 + 2] = gt_circles[(b * M + gidx) * 3 + 2];
        out_fg[row]    = fg;
        out_gtidx[row] = (float)gidx;
    }
}

// ---------------------------------------------------------------- launch

extern "C" void kernel_launch(void* const* d_in, const int* in_sizes, int n_in,
                              void* d_out, int out_size, void* d_ws, size_t ws_size,
                              hipStream_t stream) {
    const float* pd_scores  = (const float*)d_in[0];   // (B, NA, NC)
    const float* pd_circles = (const float*)d_in[1];   // (B, NA, 3)
    const float* anc        = (const float*)d_in[2];   // (NA, 2)
    const int*   gt_labels  = (const int*)  d_in[3];   // (B, M, 1)
    const float* gt_circles = (const float*)d_in[4];   // (B, M, 3)
    const float* mask_gt    = (const float*)d_in[5];   // (B, M, 1)

    // workspace layout
    char* w = (char*)d_ws;
    int*   wlist       = (int*)w;   w += (size_t)B * SPB * sizeof(int);
    float* wmetv       = (float*)w; w += (size_t)B * SPB * sizeof(float);
    float* wovv        = (float*)w; w += (size_t)B * SPB * sizeof(float);
    int*   assigned    = (int*)w;   w += (size_t)B * NA * sizeof(int);
    float* am_val      = (float*)w; w += (size_t)B * NA * sizeof(float);
    int*   pos_align_i = (int*)w;   w += (size_t)B * M * sizeof(int);
    int*   pos_ov_i    = (int*)w;   w += (size_t)B * M * sizeof(int);

    // output layout (concat in return order, float32)
    float* out        = (float*)d_out;
    float* out_labels = out;                              // B*NA
    float* out_circ   = out_labels + (size_t)B * NA;      // B*NA*3
    float* out_scores = out_circ + (size_t)B * NA * 3;    // B*NA*NC
    float* out_fg     = out_scores + (size_t)B * NA * NC; // B*NA
    float* out_gtidx  = out_fg + (size_t)B * NA;          // B*NA

    k_discover<<<NDIS, 1024, 0, stream>>>(pd_scores, pd_circles, anc, gt_labels,
                                          gt_circles, mask_gt,
                                          wlist, wmetv, wovv,
                                          assigned, am_val, pos_align_i, pos_ov_i);

    k_resolve<<<32, 256, 0, stream>>>(pd_scores, pd_circles, anc, gt_labels,
                                      gt_circles, mask_gt, wlist, wmetv, wovv,
                                      assigned, am_val, pos_align_i, pos_ov_i);

    int nq = B * NA * (NC / 4);
    k_out<<<(nq + 255) / 256, 256, 0, stream>>>(assigned, am_val,
                                                pos_align_i, pos_ov_i,
                                                gt_labels, gt_circles,
                                                out_labels, out_circ, out_scores,
                                                out_fg, out_gtidx);
}

// Round 13
// 93.801 us; speedup vs baseline: 1.5657x; 1.2054x over previous
//
#include <hip/hip_runtime.h>
#include <math.h>

#define B   8
#define NA  33600
#define M   64
#define NC  80
#define KK  13
#define EPSF 1e-9f
#define PIF 3.14159265358979323846f

#define NPOS 1536          // positive-metric capacity (<= in-circle max ~1100)
#define NBM  (B * M)       // 512
#define SPB  (M * KK)      // 832 winner slots per batch

// ---------------------------------------------------------------- helpers

__device__ __forceinline__ float circle_iou(float gx, float gy, float gr,
                                            float px, float py, float pr) {
    float dx = gx - px, dy = gy - py;
    float d  = sqrtf(dx * dx + dy * dy + 1e-12f);
    float r0sq = gr * gr, r1sq = pr * pr;
    float d1 = (r0sq - r1sq + d * d) / (2.0f * d);
    float d2 = d - d1;
    float t0 = fminf(fmaxf(d1 / fmaxf(gr, EPSF), -1.0f), 1.0f);
    float t1 = fminf(fmaxf(d2 / fmaxf(pr, EPSF), -1.0f), 1.0f);
    float a0 = r0sq * acosf(t0) - d1 * sqrtf(fmaxf(r0sq - d1 * d1, 0.0f));
    float a1 = r1sq * acosf(t1) - d2 * sqrtf(fmaxf(r1sq - d2 * d2, 0.0f));
    float lens = a0 + a1;
    float rmin = fminf(gr, pr);
    float contained = PIF * rmin * rmin;
    float inter = (d >= gr + pr) ? 0.0f
                : ((d <= fabsf(gr - pr)) ? contained : lens);
    float uni = PIF * r0sq + PIF * r1sq - inter;
    return (uni > 0.0f) ? inter / uni : 0.0f;
}

// masked overlap + align_metric for one (b, gt, anchor) — reference formula
__device__ __forceinline__ void ov_met(const float* __restrict__ pd_scores,
                                       const float* __restrict__ pd_circles,
                                       const float* __restrict__ anc,
                                       int b, int a,
                                       float gx, float gy, float gr, int gl, float gmask,
                                       float* ov_out, float* met_out) {
    float ax = anc[2 * a], ay = anc[2 * a + 1];
    float dx = ax - gx, dy = ay - gy;
    float dan = sqrtf(dx * dx + dy * dy);
    float ov = 0.0f, met = 0.0f;
    if (gmask > 0.0f && dan < gr) {
        int base = (b * NA + a) * 3;
        float px = pd_circles[base + 0];
        float py = pd_circles[base + 1];
        float pr = pd_circles[base + 2];
        float cdx = gx - px, cdy = gy - py;
        float dc = sqrtf(cdx * cdx + cdy * cdy + 1e-12f);
        float iou = (dc >= gr + pr) ? 0.0f : circle_iou(gx, gy, gr, px, py, pr);
        ov = iou * gmask;
        if (ov > 0.0f) {
            float sc = pd_scores[(size_t)(b * NA + a) * NC + gl] * gmask;
            float o2 = ov * ov;
            met = sc * (o2 * o2 * o2);          // score^1 * ov^6
        }
    }
    *ov_out = ov; *met_out = met;
}

// ---------------------------------------------------------------- K1: per-gt anchor-first discovery + top-13
// XCD-swizzled: b = bid & 7 so batch data stays in one XCD's private L2.
// In-circle test uses ONLY the anc stream; pd rows loaded predicated
// (~375 scattered L2 hits per gt instead of a dense 671 KB stream).

__global__ __launch_bounds__(1024)
void k_discover(const float* __restrict__ pd_scores, const float* __restrict__ pd_circles,
                const float* __restrict__ anc, const int* __restrict__ gt_labels,
                const float* __restrict__ gt_circles, const float* __restrict__ mask_gt,
                int* __restrict__ wlist, int* __restrict__ assigned,
                float* __restrict__ am_val) {
    int bid = blockIdx.x;
    int b   = bid & 7;                         // XCD-local batch
    int m   = bid >> 3;
    int bm  = b * M + m;
    int tid = threadIdx.x;

    // init of assigned/am_val (disjoint slice per block)
    const int SL = (B * NA) / NBM;             // 525
    int s0 = bid * SL;
    if (tid < SL) { assigned[s0 + tid] = -1; am_val[s0 + tid] = 0.0f; }

    __shared__ int   s_pcnt;
    __shared__ int   s_pa[NPOS];
    __shared__ float s_pv[NPOS];
    __shared__ int   s_win[KK];

    float gmask = mask_gt[bm];
    if (!(gmask > 0.0f)) {                     // inactive gt: empty winner list
        if (tid < KK) wlist[bm * KK + tid] = -1;
        return;
    }

    float gx = gt_circles[bm * 3 + 0];
    float gy = gt_circles[bm * 3 + 1];
    float gr = gt_circles[bm * 3 + 2];
    int gl = gt_labels[bm];
    gl = gl < 0 ? 0 : (gl > NC - 1 ? NC - 1 : gl);

    if (tid == 0) s_pcnt = 0;
    __syncthreads();

#define PROC(A_, AX_, AY_) do {                                                \
        float dxa_ = (AX_) - gx, dya_ = (AY_) - gy;                            \
        if (sqrtf(dxa_ * dxa_ + dya_ * dya_) < gr) {                           \
            size_t pb_ = ((size_t)b * NA + (A_)) * 3;                          \
            float px_ = pd_circles[pb_], py_ = pd_circles[pb_ + 1], pr_ = pd_circles[pb_ + 2]; \
            float cdx_ = gx - px_, cdy_ = gy - py_;                            \
            float dc_ = sqrtf(cdx_ * cdx_ + cdy_ * cdy_ + 1e-12f);             \
            if (dc_ < gr + pr_) {                                              \
                float ov_ = circle_iou(gx, gy, gr, px_, py_, pr_);             \
                if (ov_ > 0.0f) {                                              \
                    float sc_ = pd_scores[((size_t)b * NA + (A_)) * NC + gl];  \
                    float o2_ = ov_ * ov_;                                     \
                    float met_ = sc_ * (o2_ * o2_ * o2_);                      \
                    if (met_ > 0.0f) {                                         \
                        int p_ = atomicAdd(&s_pcnt, 1);                        \
                        if (p_ < NPOS) { s_pa[p_] = (A_); s_pv[p_] = met_; }   \
                    } } } } } while (0)

    #pragma unroll 2
    for (int q = tid; q < NA / 2; q += 1024) {
        float4 ap = reinterpret_cast<const float4*>(anc)[q];   // anchors 2q, 2q+1
        PROC(2 * q,     ap.x, ap.y);
        PROC(2 * q + 1, ap.z, ap.w);
    }
#undef PROC
    __syncthreads();
    int pcnt = s_pcnt; if (pcnt > NPOS) pcnt = NPOS;

    if (tid >= 64) return;                     // selection on wave 0, no barriers

    // 13 rounds of argmax (val desc, anchor asc) == lax.top_k order
    for (int k = 0; k < KK; k++) {
        float bv = 0.0f; int ba = 0x7fffffff; int bp = -1;
        for (int i = tid; i < pcnt; i += 64) {
            float v = s_pv[i];
            if (v > 0.0f) {
                int a = s_pa[i];
                if (v > bv || (v == bv && a < ba)) { bv = v; ba = a; bp = i; }
            }
        }
        for (int off = 32; off > 0; off >>= 1) {
            float v2 = __shfl_xor(bv, off);
            int   a2 = __shfl_xor(ba, off);
            int   p2 = __shfl_xor(bp, off);
            if (v2 > bv || (v2 == bv && a2 < ba)) { bv = v2; ba = a2; bp = p2; }
        }
        if (tid == 0) {
            if (bp >= 0) { s_win[k] = ba; s_pv[bp] = -1.0f; }
            else s_win[k] = -2;
        }
    }

    // zero-fill WITHOUT gathers: met==0  <=>  anchor absent from positive list
    // -> lowest absent indices (lax.top_k zero tie-break)
    int defmask = 0;
    for (int k = 0; k < KK; k++) if (s_win[k] == -2) defmask |= (1 << k);
    if (defmask) {
        int base = 0;
        while (defmask && base < NA) {
            int idx = base + tid;
            bool freez = (idx < NA);
            for (int i = 0; i < pcnt; i++)
                freez = freez && (s_pa[i] != idx);
            unsigned long long msk = __ballot(freez);
            while (msk && defmask) {
                int bit = __ffsll((long long)msk) - 1; msk &= msk - 1;
                int k2  = __ffs(defmask) - 1;          defmask &= defmask - 1;
                if (tid == 0) s_win[k2] = base + bit;
            }
            base += 64;
        }
        while (defmask) {
            int k2 = __ffs(defmask) - 1; defmask &= defmask - 1;
            if (tid == 0) s_win[k2] = -1;
        }
    }

    // winners enter mask_pos only if anchor center inside the gt circle
    if (tid < KK) {
        int a = s_win[tid];
        int outv = -1;
        if (a >= 0) {
            float ax = anc[2 * a], ay = anc[2 * a + 1];
            float dx = ax - gx, dy = ay - gy;
            if (sqrtf(dx * dx + dy * dy) < gr) outv = a;
        }
        wlist[bm * KK + tid] = outv;
    }
}

// ---------------------------------------------------------------- K2: per-batch resolve + pos maxima
// LDS u8 histogram over the 832 winner slots (no pre-zeroed global needed).

__global__ __launch_bounds__(1024)
void k_resolve(const float* __restrict__ pd_scores, const float* __restrict__ pd_circles,
               const float* __restrict__ anc, const int* __restrict__ gt_labels,
               const float* __restrict__ gt_circles, const float* __restrict__ mask_gt,
               const int* __restrict__ wlist,
               int* __restrict__ assigned, float* __restrict__ am_val,
               int* __restrict__ pos_align_i, int* __restrict__ pos_ov_i) {
    int b = blockIdx.x;
    int tid = threadIdx.x;

    __shared__ unsigned int s_cnt[NA / 4 + 1];   // u8-packed counts, 33.6 KB
    __shared__ float s_gx[M], s_gy[M], s_gr[M];
    __shared__ int   s_gl[M], s_act[M];
    __shared__ int   s_posa[M], s_poso[M];
    __shared__ int   s_multi[512];
    __shared__ int   s_nm;

    if (tid < M) {
        int gi = b * M + tid;
        s_act[tid] = mask_gt[gi] > 0.0f;
        s_gx[tid] = gt_circles[gi * 3 + 0];
        s_gy[tid] = gt_circles[gi * 3 + 1];
        s_gr[tid] = gt_circles[gi * 3 + 2];
        int l = gt_labels[gi];
        s_gl[tid] = l < 0 ? 0 : (l > NC - 1 ? NC - 1 : l);
        s_posa[tid] = 0; s_poso[tid] = 0;
    }
    if (tid == 0) s_nm = 0;
    for (int w = tid; w < NA / 4 + 1; w += 1024) s_cnt[w] = 0;
    __syncthreads();

    // histogram: count gts listing each anchor (in-circle-filtered winners)
    int a = -1, m = -1; unsigned int prev = 0;
    if (tid < SPB) {
        a = wlist[b * SPB + tid];
        m = tid / KK;
        if (a >= 0) {
            unsigned int sh = 8u * (a & 3);
            unsigned int old = atomicAdd(&s_cnt[a >> 2], 1u << sh);
            prev = (old >> sh) & 0xFFu;          // my slot's order among dupes
        }
    }
    __syncthreads();

    // classify; singles resolve immediately; first-toucher of multis enqueues
    bool single = false;
    if (a >= 0) {
        unsigned int c = (s_cnt[a >> 2] >> (8u * (a & 3))) & 0xFFu;
        if (c == 1u) single = true;
        else if (prev == 0u) { int i2 = atomicAdd(&s_nm, 1); s_multi[i2] = a; }
    }
    if (single) {
        int i = b * NA + a;
        float gx = s_gx[m], gy = s_gy[m], gr = s_gr[m];
        float px = pd_circles[(size_t)i * 3 + 0];
        float py = pd_circles[(size_t)i * 3 + 1];
        float pr = pd_circles[(size_t)i * 3 + 2];
        float cdx = gx - px, cdy = gy - py;
        float dc = sqrtf(cdx * cdx + cdy * cdy + 1e-12f);
        float ov = (dc >= gr + pr) ? 0.0f : circle_iou(gx, gy, gr, px, py, pr);
        float met = 0.0f;
        if (ov > 0.0f) {
            float sc = pd_scores[(size_t)i * NC + s_gl[m]];
            float o2 = ov * ov;
            met = sc * (o2 * o2 * o2);
        }
        assigned[i] = m;
        am_val[i]   = met;
        atomicMax(&s_posa[m], __float_as_int(met));   // values >= 0
        atomicMax(&s_poso[m], __float_as_int(ov));
    }
    __syncthreads();

    // multis: one anchor per wave; lane = gt; argmax over masked overlaps
    // (jnp.argmax semantics: lowest gt index wins ties; all-zero row -> 0)
    int lane = tid & 63, w = tid >> 6;           // 16 waves
    int nm = s_nm;
    for (int r = w; r < nm; r += 16) {
        int am_ = s_multi[r];
        int i = b * NA + am_;
        float ax = anc[2 * am_], ay = anc[2 * am_ + 1];
        float px = pd_circles[(size_t)i * 3 + 0];
        float py = pd_circles[(size_t)i * 3 + 1];
        float pr = pd_circles[(size_t)i * 3 + 2];
        float ov = 0.0f;
        if (s_act[lane]) {
            float gx = s_gx[lane], gy = s_gy[lane], gr = s_gr[lane];
            float dx = ax - gx, dy = ay - gy;
            if (sqrtf(dx * dx + dy * dy) < gr) {
                float cdx = gx - px, cdy = gy - py;
                float dc = sqrtf(cdx * cdx + cdy * cdy + 1e-12f);
                ov = (dc >= gr + pr) ? 0.0f : circle_iou(gx, gy, gr, px, py, pr);
            }
        }
        float bv = ov; int bmx = lane;
        for (int off = 32; off > 0; off >>= 1) {
            float v2 = __shfl_xor(bv, off);
            int   m2 = __shfl_xor(bmx, off);
            if (v2 > bv || (v2 == bv && m2 < bmx)) { bv = v2; bmx = m2; }
        }
        if (lane == 0) {
            float met = 0.0f;
            if (bv > 0.0f) {
                float sc = pd_scores[(size_t)i * NC + s_gl[bmx]];
                float o2 = bv * bv;
                met = sc * (o2 * o2 * o2);
            }
            assigned[i] = bmx;
            am_val[i]   = met;
            atomicMax(&s_posa[bmx], __float_as_int(met));
            atomicMax(&s_poso[bmx], __float_as_int(bv));
        }
    }
    __syncthreads();

    if (tid < M) {
        pos_align_i[b * M + tid] = s_posa[tid];
        pos_ov_i[b * M + tid]    = s_poso[tid];
    }
}

// ---------------------------------------------------------------- K3: fused outputs (93 MB write)

__global__ void k_out(const int* __restrict__ assigned, const float* __restrict__ am_val,
                      const int* __restrict__ pos_align_i, const int* __restrict__ pos_ov_i,
                      const int* __restrict__ gt_labels, const float* __restrict__ gt_circles,
                      float* __restrict__ out_labels, float* __restrict__ out_circ,
                      float* __restrict__ out_scores, float* __restrict__ out_fg,
                      float* __restrict__ out_gtidx) {
    const int QPR = NC / 4;                      // 20 float4s per score row
    int q = blockIdx.x * blockDim.x + threadIdx.x;
    if (q >= B * NA * QPR) return;
    int row = q / QPR;
    int c0  = (q - row * QPR) * 4;
    int b   = row / NA;

    int g = assigned[row];
    int gidx = 0; float fg = 0.0f; float norm = 0.0f;
    if (g >= 0) {
        gidx = g; fg = 1.0f;
        float pa = __int_as_float(pos_align_i[b * M + g]);
        float po = __int_as_float(pos_ov_i[b * M + g]);
        norm = am_val[row] * po / (pa + EPSF);
    }
    int rawl = gt_labels[b * M + gidx];
    int lbl = rawl < 0 ? 0 : rawl;               // clip(.., 0, None)

    float4 v = make_float4(0.f, 0.f, 0.f, 0.f);
    if (g >= 0) {
        int off = lbl - c0;
        if (off >= 0 && off < 4) ((float*)&v)[off] = norm;
    }
    reinterpret_cast<float4*>(out_scores)[q] = v;

    if (c0 == 0) {
        out_labels[row] = (float)lbl;
        out_circ[(size_t)row * 3 + 0] = gt_circles[(b * M + gidx) * 3 + 0];
        out_circ[(size_t)row * 3 + 1] = gt_circles[(b * M + gidx) * 3 + 1];
        out_circ[(size_t)row * 3 + 2] = gt_circles[(b * M + gidx) * 3 + 2];
        out_fg[row]    = fg;
        out_gtidx[row] = (float)gidx;
    }
}

// ---------------------------------------------------------------- launch

extern "C" void kernel_launch(void* const* d_in, const int* in_sizes, int n_in,
                              void* d_out, int out_size, void* d_ws, size_t ws_size,
                              hipStream_t stream) {
    const float* pd_scores  = (const float*)d_in[0];   // (B, NA, NC)
    const float* pd_circles = (const float*)d_in[1];   // (B, NA, 3)
    const float* anc        = (const float*)d_in[2];   // (NA, 2)
    const int*   gt_labels  = (const int*)  d_in[3];   // (B, M, 1)
    const float* gt_circles = (const float*)d_in[4];   // (B, M, 3)
    const float* mask_gt    = (const float*)d_in[5];   // (B, M, 1)

    // workspace layout
    char* w = (char*)d_ws;
    int*   wlist       = (int*)w;   w += (size_t)NBM * KK * sizeof(int);
    int*   assigned    = (int*)w;   w += (size_t)B * NA * sizeof(int);
    float* am_val      = (float*)w; w += (size_t)B * NA * sizeof(float);
    int*   pos_align_i = (int*)w;   w += (size_t)B * M * sizeof(int);
    int*   pos_ov_i    = (int*)w;   w += (size_t)B * M * sizeof(int);

    // output layout (concat in return order, float32)
    float* out        = (float*)d_out;
    float* out_labels = out;                              // B*NA
    float* out_circ   = out_labels + (size_t)B * NA;      // B*NA*3
    float* out_scores = out_circ + (size_t)B * NA * 3;    // B*NA*NC
    float* out_fg     = out_scores + (size_t)B * NA * NC; // B*NA
    float* out_gtidx  = out_fg + (size_t)B * NA;          // B*NA

    k_discover<<<NBM, 1024, 0, stream>>>(pd_scores, pd_circles, anc, gt_labels,
                                         gt_circles, mask_gt,
                                         wlist, assigned, am_val);

    k_resolve<<<B, 1024, 0, stream>>>(pd_scores, pd_circles, anc, gt_labels,
                                      gt_circles, mask_gt, wlist,
                                      assigned, am_val, pos_align_i, pos_ov_i);

    int nq = B * NA * (NC / 4);
    k_out<<<(nq + 255) / 256, 256, 0, stream>>>(assigned, am_val,
                                                pos_align_i, pos_ov_i,
                                                gt_labels, gt_circles,
                                                out_labels, out_circ, out_scores,
                                                out_fg, out_gtidx);
}